// Round 9
// baseline (190.782 us; speedup 1.0000x reference)
//
#include <hip/hip_runtime.h>

// LSS view transform: chunked-gather, d-in-lane run-merged binning, 64-way
// sharded cursors, cell-major atomic accumulator, fused prep kernel.
// out[b,c,cell] = sum_{(pix,d)->cell} img[b,c,pix] * dp[b,d,pix]
// Round-9 changes:
//  - binning is d-in-lane (wave = one ray, lane = depth bin): consecutive-d
//    same-cell runs merge into ONE entry with segmented-scan summed weight
//    (entry count ~800K -> ~460K => gather row-reads drop 1.7x).
//  - NSHARD 16 -> 64 (per-ray entries put ~2000 increments on hot cells).
//  - dp transposed to [b,pix,d] (lane-contiguous weight loads in fill).
//  - k_prep fuses img-transpose + dp-transpose + count (10 -> 8 dispatches).
//  - gather: 3840 blocks x 4 contiguous chunks, accumulator carried across
//    chunks; XCD-balanced for any entry total; L1 row-reuse across ~18 cells.
constexpr int IMG_H = 48, IMG_W = 160;
constexpr int HW    = IMG_H * IMG_W;          // 7680
constexpr int BEV_H = 128, BEV_W = 128;
constexpr int NCELL = BEV_H * BEV_W;          // 16384 per batch
constexpr int C_DIM = 128, D_DIM = 64, B_DIM = 2;
constexpr int NCELL_TOT = B_DIM * NCELL;      // 32768
constexpr int NPIX_TOT  = B_DIM * HW;         // 15360
constexpr int NPTS      = NPIX_TOT * D_DIM;   // 983040
constexpr int CHUNK = 64;
constexpr int NSHARD = 64;
constexpr int GATHER_BLOCKS = 3840;
constexpr int CHUNKS_PER_BLOCK = NPTS / CHUNK / GATHER_BLOCKS;   // 4
constexpr float X_MIN = -51.2f, Y_MIN = -51.2f;
constexpr float RES_X = 102.4f / 128.0f;
constexpr float RES_Y = 102.4f / 128.0f;

// ---- ws layout (4-byte words), ~43 MB total ----
constexpr size_t WS_IMG_T = 0;                                      // float[B*HW*C] 1966080
constexpr size_t WS_DP_T  = WS_IMG_T + (size_t)B_DIM * HW * C_DIM;  // float[B*HW*D] 983040
constexpr size_t WS_HIST2 = WS_DP_T + (size_t)B_DIM * HW * D_DIM;   // int[NSHARD*32768] 2097152
constexpr size_t WS_OUT_T = WS_HIST2 + (size_t)NSHARD * NCELL_TOT;  // float[NCELL_TOT*C] (adjacent -> fused memset)
constexpr size_t WS_HIST  = WS_OUT_T + (size_t)NCELL_TOT * C_DIM;   // int[32768]
constexpr size_t WS_OFFS  = WS_HIST + NCELL_TOT;                    // int[32769] (+3 pad)
constexpr size_t WS_EKEY  = WS_OFFS + NCELL_TOT + 4;                // int[NPTS] worst case
constexpr size_t WS_EW16  = WS_EKEY + NPTS;                         // ushort[NPTS]

__device__ inline void make_ray(const float* __restrict__ K, int b, float gx, float gy,
                                float& rx, float& ry, float& rz) {
    const float* Kb = K + b * 9;
    const float a00 = Kb[0], a01 = Kb[1], a02 = Kb[2];
    const float a10 = Kb[3], a11 = Kb[4], a12 = Kb[5];
    const float a20 = Kb[6], a21 = Kb[7], a22 = Kb[8];
    const float det = a00 * (a11 * a22 - a12 * a21)
                    - a01 * (a10 * a22 - a12 * a20)
                    + a02 * (a10 * a21 - a11 * a20);
    const float inv = 1.0f / det;
    const float i00 =  (a11 * a22 - a12 * a21) * inv;
    const float i01 = -(a01 * a22 - a02 * a21) * inv;
    const float i02 =  (a01 * a12 - a02 * a11) * inv;
    const float i10 = -(a10 * a22 - a12 * a20) * inv;
    const float i11 =  (a00 * a22 - a02 * a20) * inv;
    const float i12 = -(a00 * a12 - a02 * a10) * inv;
    const float i20 =  (a10 * a21 - a11 * a20) * inv;
    const float i21 = -(a00 * a21 - a01 * a20) * inv;
    const float i22 =  (a00 * a11 - a01 * a10) * inv;
    rx = i00 * gx + i01 * gy + i02;
    ry = i10 * gx + i11 * gy + i12;
    rz = i20 * gx + i21 * gy + i22;
}

// Global cell id (b*NCELL + cell) or -1 for ray (b,pix) at depth bin d.
__device__ inline int gcell_ray(int b, int pix, int d,
                                const float* __restrict__ dv,
                                const float* __restrict__ K,
                                const float* __restrict__ T) {
    const int h = pix / IMG_W, w = pix % IMG_W;
    float rx, ry, rz;
    make_ray(K, b, (float)w, (float)h, rx, ry, rz);
    const float* Tb = T + b * 16;
    const float dep = dv[d];                       // lane-coalesced (lane == d)
    const float px = dep * rx, py = dep * ry, pz = dep * rz;
    const float x = Tb[0] * px + Tb[1] * py + Tb[2]  * pz + Tb[3];
    const float y = Tb[4] * px + Tb[5] * py + Tb[6]  * pz + Tb[7];
    const float z = Tb[8] * px + Tb[9] * py + Tb[10] * pz + Tb[11];
    const int bx = (int)((x - X_MIN) / RES_X);     // truncate-toward-zero == astype(int32)
    const int by = (int)((y - Y_MIN) / RES_Y);
    const bool valid = (bx >= 0) && (bx < BEV_W) && (by >= 0) && (by < BEV_H) && (z > 0.0f);
    return valid ? (b * NCELL + by * BEV_W + bx) : -1;
}

// Run structure across the wave (lanes = consecutive d of one ray).
struct RunInfo { int leader_idx; bool is_tail; };
__device__ inline RunInfo wave_runs_d(int gcell, int lane) {
    const int left = __shfl_up(gcell, 1);          // width 64
    const bool is_leader = (lane == 0) || (left != gcell);
    const unsigned long long lmask = __ballot(is_leader);
    const unsigned long long below =
        lmask & ((lane == 63) ? ~0ULL : ((1ULL << (lane + 1)) - 1ULL));
    RunInfo r;
    r.leader_idx = 63 - __clzll((long long)below);
    r.is_tail = (lane == 63) || ((lmask >> (lane + 1)) & 1ULL);
    return r;
}

__device__ inline int shard_of(int pix) { return (pix ^ (pix >> 6)) & (NSHARD - 1); }

// ---- K1 fused prep: img transpose + dp transpose + run count ----
constexpr int NB_IMG = (HW / 32) * (C_DIM / 32) * B_DIM;   // 1920
constexpr int NB_DP  = (HW / 32) * (D_DIM / 32) * B_DIM;   // 960
constexpr int NB_CNT = NPTS / 256;                         // 3840
__global__ __launch_bounds__(256) void k_prep(const float* __restrict__ img,
                                              const float* __restrict__ dp,
                                              const float* __restrict__ dv,
                                              const float* __restrict__ K,
                                              const float* __restrict__ T,
                                              float* __restrict__ img_t,
                                              float* __restrict__ dp_t,
                                              int* __restrict__ hist2) {
    int bid = blockIdx.x;
    if (bid < NB_IMG + NB_DP) {
        // tiled 32x32 transpose: src[b, r, pix] -> dst[b, pix, r]
        const float* src; float* dst; int rows;
        if (bid < NB_IMG) { src = img; dst = img_t; rows = C_DIM; }
        else              { bid -= NB_IMG; src = dp; dst = dp_t; rows = D_DIM; }
        const int tiles_c = rows / 32;
        const int b = bid / ((HW / 32) * tiles_c);
        const int r = bid % ((HW / 32) * tiles_c);
        const int ctile = r / (HW / 32), ptile = r % (HW / 32);
        __shared__ float tile[32][33];
        const int tx = threadIdx.x & 31, ty = threadIdx.x >> 5;   // (32, 8)
        const int pix0 = ptile * 32, c0 = ctile * 32;
        #pragma unroll
        for (int j = 0; j < 32; j += 8)
            tile[ty + j][tx] = src[((size_t)(b * rows + c0 + ty + j)) * HW + pix0 + tx];
        __syncthreads();
        #pragma unroll
        for (int j = 0; j < 32; j += 8)
            dst[((size_t)(b * HW + pix0 + ty + j)) * rows + c0 + tx] = tile[tx][ty + j];
    } else {
        // count merged runs; wave = one ray, lane = depth bin
        const int tid = (bid - NB_IMG - NB_DP) * 256 + threadIdx.x;   // < NPTS
        const int lane = threadIdx.x & 63;                            // = d
        const int wid = tid >> 6;                                     // ray id
        const int b = wid / HW, pix = wid % HW;
        const int gcell = gcell_ray(b, pix, lane, dv, K, T);
        const RunInfo ri = wave_runs_d(gcell, lane);
        if (ri.is_tail && gcell >= 0)
            atomicAdd(&hist2[(size_t)shard_of(pix) * NCELL_TOT + gcell], 1);
    }
}

// ---- K2: reduce shards -> per-cell totals ----
__global__ __launch_bounds__(256) void k_reduce(const int* __restrict__ hist2,
                                                int* __restrict__ hist) {
    const int cell = blockIdx.x * 256 + threadIdx.x;  // 128 blocks exact
    int s = 0;
    #pragma unroll
    for (int sh = 0; sh < NSHARD; ++sh)
        s += hist2[(size_t)sh * NCELL_TOT + cell];
    hist[cell] = s;
}

// ---- K3: exclusive prefix scan over hist[32768] -> offs[32769] ----
__global__ __launch_bounds__(1024) void k_scan(const int* __restrict__ hist,
                                               int* __restrict__ offs) {
    __shared__ int lds[1024];
    const int t = threadIdx.x;
    int h[32];
    int s = 0;
    const int base = t * 32;
    #pragma unroll
    for (int k = 0; k < 32; ++k) { h[k] = hist[base + k]; s += h[k]; }
    lds[t] = s;
    __syncthreads();
    for (int off = 1; off < 1024; off <<= 1) {
        int v = (t >= off) ? lds[t - off] : 0;
        __syncthreads();
        lds[t] += v;
        __syncthreads();
    }
    int run = lds[t] - s;
    #pragma unroll
    for (int k = 0; k < 32; ++k) {
        offs[base + k] = run;
        run += h[k];
    }
    if (t == 1023) offs[NCELL_TOT] = lds[1023];
}

// ---- K4: per-cell shard prefix; hist2 becomes cursor bases in place ----
__global__ __launch_bounds__(256) void k_shardbase(int* __restrict__ hist2,
                                                   const int* __restrict__ offs) {
    const int cell = blockIdx.x * 256 + threadIdx.x;  // 128 blocks exact
    int run = offs[cell];
    #pragma unroll
    for (int sh = 0; sh < NSHARD; ++sh) {
        const size_t idx = (size_t)sh * NCELL_TOT + cell;
        const int cnt = hist2[idx];
        hist2[idx] = run;
        run += cnt;
    }
}

// ---- K5: fill merged entries. Wave = one ray; segmented inclusive scan of dp
// over equal-cell runs; run tail emits (key, summed weight). ----
__global__ __launch_bounds__(256) void k_fill(const float* __restrict__ dp_t,
                                              const float* __restrict__ dv,
                                              const float* __restrict__ K,
                                              const float* __restrict__ T,
                                              int* __restrict__ cursor2,   // = hist2 (bases)
                                              int* __restrict__ ekey,
                                              unsigned short* __restrict__ ew16) {
    const int tid = blockIdx.x * 256 + threadIdx.x;   // < NPTS
    const int lane = threadIdx.x & 63;                // = d
    const int wid = tid >> 6;                         // ray id
    const int b = wid / HW, pix = wid % HW;
    const int gcell = gcell_ray(b, pix, lane, dv, K, T);
    const RunInfo ri = wave_runs_d(gcell, lane);
    const float p = dp_t[((size_t)(b * HW + pix)) * D_DIM + lane];   // lane-contiguous
    // segmented inclusive scan (Hillis-Steele with head clamp)
    float val = p;
    #pragma unroll
    for (int dlt = 1; dlt < 64; dlt <<= 1) {
        const float up = __shfl_up(val, dlt);
        val = (lane - dlt >= ri.leader_idx) ? val + up : val;
    }
    if (ri.is_tail && gcell >= 0) {
        const int slot = atomicAdd(&cursor2[(size_t)shard_of(pix) * NCELL_TOT + gcell], 1);
        ekey[slot] = (gcell << 13) | pix;
        ew16[slot] = (unsigned short)__float2uint_rn(fminf(val * 65535.0f, 65535.0f));
    }
}

// ---- K6: chunked segmented reduction. One wave/block, 4 contiguous chunks,
// thread = 2 channels (float2); accumulator carried across chunk boundaries;
// flushes to cell-major out_t (128 consecutive floats per flush). ----
__global__ __launch_bounds__(64) void k_gather(
    const float* __restrict__ img_t,
    const int* __restrict__ offs,     // offs[NCELL_TOT] = total entry count
    const int* __restrict__ ekey,
    const unsigned short* __restrict__ ew16,
    float* __restrict__ out_t)
{
    const int total = offs[NCELL_TOT];
    __shared__ int   s_key[CHUNK];
    __shared__ float s_w[CHUNK];

    const int c2 = threadIdx.x * 2;                   // channels c2, c2+1
    int prev = -1;
    float2 acc = make_float2(0.0f, 0.0f);

    for (int cc = 0; cc < CHUNKS_PER_BLOCK; ++cc) {
        const int base = (blockIdx.x * CHUNKS_PER_BLOCK + cc) * CHUNK;
        if (base >= total) break;
        __syncthreads();                              // reuse s_key safely
        {
            const int i = threadIdx.x;
            const int idx = min(base + i, total - 1);
            s_key[i] = ekey[idx];                     // pad = dup of last key
            s_w[i]   = (base + i < total) ? (float)ew16[base + i] * (1.0f / 65535.0f)
                                          : 0.0f;     // pad weight 0 -> no-op
        }
        __syncthreads();
        if (prev < 0) prev = s_key[0] >> 13;
        #pragma unroll 8
        for (int k = 0; k < CHUNK; ++k) {
            const int key = s_key[k];                 // LDS broadcast (wave-uniform)
            const float wgt = s_w[k];
            const int gcell = key >> 13;
            const int pix = key & 8191;
            const int b = gcell >> 14;
            const float2 v = *reinterpret_cast<const float2*>(
                &img_t[((size_t)(b * HW + pix)) * C_DIM + c2]);   // 8B/lane
            if (gcell != prev) {                      // wave-uniform branch
                float* o = &out_t[(size_t)prev * C_DIM + c2];
                atomicAdd(o, acc.x);
                atomicAdd(o + 1, acc.y);
                acc = make_float2(0.0f, 0.0f);
                prev = gcell;
            }
            acc.x = fmaf(v.x, wgt, acc.x);
            acc.y = fmaf(v.y, wgt, acc.y);
        }
    }
    if (prev >= 0) {
        float* o = &out_t[(size_t)prev * C_DIM + c2];
        atomicAdd(o, acc.x);
        atomicAdd(o + 1, acc.y);
    }
}

// ---- K7: untranspose out_t[b][cell][c] -> out[b][c][cell] ----
__global__ __launch_bounds__(256) void k_untranspose(const float* __restrict__ out_t,
                                                     float* __restrict__ out) {
    __shared__ float tile[32][33];
    const int b = blockIdx.z;
    const int tx = threadIdx.x, ty = threadIdx.y;      // block (32, 8)
    const int cell0 = blockIdx.x * 32, c0 = blockIdx.y * 32;
    const float* src = out_t + (size_t)b * NCELL * C_DIM;
    #pragma unroll
    for (int j = 0; j < 32; j += 8)
        tile[ty + j][tx] = src[((size_t)(cell0 + ty + j)) * C_DIM + c0 + tx];
    __syncthreads();
    #pragma unroll
    for (int j = 0; j < 32; j += 8)
        out[((size_t)(b * C_DIM + c0 + ty + j)) * NCELL + cell0 + tx] = tile[tx][ty + j];
}

extern "C" void kernel_launch(void* const* d_in, const int* in_sizes, int n_in,
                              void* d_out, int out_size, void* d_ws, size_t ws_size,
                              hipStream_t stream) {
    const float* img = (const float*)d_in[0];
    const float* dp  = (const float*)d_in[1];
    const float* dv  = (const float*)d_in[2];
    const float* K   = (const float*)d_in[3];
    const float* T   = (const float*)d_in[4];
    float* out = (float*)d_out;

    float* ws_f   = (float*)d_ws;
    float* img_t  = ws_f + WS_IMG_T;
    float* dp_t   = ws_f + WS_DP_T;
    int*   hist2  = (int*)d_ws + WS_HIST2;
    float* out_t  = ws_f + WS_OUT_T;
    int*   hist   = (int*)d_ws + WS_HIST;
    int*   offs   = (int*)d_ws + WS_OFFS;
    int*   ekey   = (int*)d_ws + WS_EKEY;
    unsigned short* ew16 = (unsigned short*)((int*)d_ws + WS_EW16);

    // hist2 and out_t adjacent -> one fused memset (8 MB + 16 MB)
    hipMemsetAsync(hist2, 0,
                   ((size_t)NSHARD * NCELL_TOT + (size_t)NCELL_TOT * C_DIM) * sizeof(int),
                   stream);

    k_prep<<<NB_IMG + NB_DP + NB_CNT, 256, 0, stream>>>(img, dp, dv, K, T,
                                                        img_t, dp_t, hist2);
    k_reduce<<<NCELL_TOT / 256, 256, 0, stream>>>(hist2, hist);
    k_scan<<<1, 1024, 0, stream>>>(hist, offs);
    k_shardbase<<<NCELL_TOT / 256, 256, 0, stream>>>(hist2, offs);
    k_fill<<<NPTS / 256, 256, 0, stream>>>(dp_t, dv, K, T, hist2, ekey, ew16);
    k_gather<<<GATHER_BLOCKS, 64, 0, stream>>>(img_t, offs, ekey, ew16, out_t);
    k_untranspose<<<dim3(NCELL / 32, C_DIM / 32, B_DIM), dim3(32, 8), 0, stream>>>(
        out_t, out);
}

// Round 10
// 172.536 us; speedup vs baseline: 1.1058x; 1.1058x over previous
//
#include <hip/hip_runtime.h>

// LSS view transform: chunked-gather, d-in-lane run-merged binning, 64-way
// sharded cursors, cell-major atomic accumulator, fused prep kernel.
// out[b,c,cell] = sum_{(pix,d)->cell} img[b,c,pix] * dp[b,d,pix]
// Round-10 change: gather grid back to one chunk per block (15360 blocks,
// early-exit when past total). Round-9's 3840x4-chunk grid left only ~1800
// blocks active after entry-merging shrank total to ~460K -> 23% occupancy,
// 64 us. Same per-block structure as round-8's proven 40 us kernel, now with
// 1.7x fewer active blocks (merged entries).
constexpr int IMG_H = 48, IMG_W = 160;
constexpr int HW    = IMG_H * IMG_W;          // 7680
constexpr int BEV_H = 128, BEV_W = 128;
constexpr int NCELL = BEV_H * BEV_W;          // 16384 per batch
constexpr int C_DIM = 128, D_DIM = 64, B_DIM = 2;
constexpr int NCELL_TOT = B_DIM * NCELL;      // 32768
constexpr int NPIX_TOT  = B_DIM * HW;         // 15360
constexpr int NPTS      = NPIX_TOT * D_DIM;   // 983040
constexpr int CHUNK = 64;
constexpr int NSHARD = 64;
constexpr float X_MIN = -51.2f, Y_MIN = -51.2f;
constexpr float RES_X = 102.4f / 128.0f;
constexpr float RES_Y = 102.4f / 128.0f;

// ---- ws layout (4-byte words), ~43 MB total ----
constexpr size_t WS_IMG_T = 0;                                      // float[B*HW*C] 1966080
constexpr size_t WS_DP_T  = WS_IMG_T + (size_t)B_DIM * HW * C_DIM;  // float[B*HW*D] 983040
constexpr size_t WS_HIST2 = WS_DP_T + (size_t)B_DIM * HW * D_DIM;   // int[NSHARD*32768] 2097152
constexpr size_t WS_OUT_T = WS_HIST2 + (size_t)NSHARD * NCELL_TOT;  // float[NCELL_TOT*C] (adjacent -> fused memset)
constexpr size_t WS_HIST  = WS_OUT_T + (size_t)NCELL_TOT * C_DIM;   // int[32768]
constexpr size_t WS_OFFS  = WS_HIST + NCELL_TOT;                    // int[32769] (+3 pad)
constexpr size_t WS_EKEY  = WS_OFFS + NCELL_TOT + 4;                // int[NPTS] worst case
constexpr size_t WS_EW16  = WS_EKEY + NPTS;                         // ushort[NPTS]

__device__ inline void make_ray(const float* __restrict__ K, int b, float gx, float gy,
                                float& rx, float& ry, float& rz) {
    const float* Kb = K + b * 9;
    const float a00 = Kb[0], a01 = Kb[1], a02 = Kb[2];
    const float a10 = Kb[3], a11 = Kb[4], a12 = Kb[5];
    const float a20 = Kb[6], a21 = Kb[7], a22 = Kb[8];
    const float det = a00 * (a11 * a22 - a12 * a21)
                    - a01 * (a10 * a22 - a12 * a20)
                    + a02 * (a10 * a21 - a11 * a20);
    const float inv = 1.0f / det;
    const float i00 =  (a11 * a22 - a12 * a21) * inv;
    const float i01 = -(a01 * a22 - a02 * a21) * inv;
    const float i02 =  (a01 * a12 - a02 * a11) * inv;
    const float i10 = -(a10 * a22 - a12 * a20) * inv;
    const float i11 =  (a00 * a22 - a02 * a20) * inv;
    const float i12 = -(a00 * a12 - a02 * a10) * inv;
    const float i20 =  (a10 * a21 - a11 * a20) * inv;
    const float i21 = -(a00 * a21 - a01 * a20) * inv;
    const float i22 =  (a00 * a11 - a01 * a10) * inv;
    rx = i00 * gx + i01 * gy + i02;
    ry = i10 * gx + i11 * gy + i12;
    rz = i20 * gx + i21 * gy + i22;
}

// Global cell id (b*NCELL + cell) or -1 for ray (b,pix) at depth bin d.
__device__ inline int gcell_ray(int b, int pix, int d,
                                const float* __restrict__ dv,
                                const float* __restrict__ K,
                                const float* __restrict__ T) {
    const int h = pix / IMG_W, w = pix % IMG_W;
    float rx, ry, rz;
    make_ray(K, b, (float)w, (float)h, rx, ry, rz);
    const float* Tb = T + b * 16;
    const float dep = dv[d];                       // lane-coalesced (lane == d)
    const float px = dep * rx, py = dep * ry, pz = dep * rz;
    const float x = Tb[0] * px + Tb[1] * py + Tb[2]  * pz + Tb[3];
    const float y = Tb[4] * px + Tb[5] * py + Tb[6]  * pz + Tb[7];
    const float z = Tb[8] * px + Tb[9] * py + Tb[10] * pz + Tb[11];
    const int bx = (int)((x - X_MIN) / RES_X);     // truncate-toward-zero == astype(int32)
    const int by = (int)((y - Y_MIN) / RES_Y);
    const bool valid = (bx >= 0) && (bx < BEV_W) && (by >= 0) && (by < BEV_H) && (z > 0.0f);
    return valid ? (b * NCELL + by * BEV_W + bx) : -1;
}

// Run structure across the wave (lanes = consecutive d of one ray).
struct RunInfo { int leader_idx; bool is_tail; };
__device__ inline RunInfo wave_runs_d(int gcell, int lane) {
    const int left = __shfl_up(gcell, 1);          // width 64
    const bool is_leader = (lane == 0) || (left != gcell);
    const unsigned long long lmask = __ballot(is_leader);
    const unsigned long long below =
        lmask & ((lane == 63) ? ~0ULL : ((1ULL << (lane + 1)) - 1ULL));
    RunInfo r;
    r.leader_idx = 63 - __clzll((long long)below);
    r.is_tail = (lane == 63) || ((lmask >> (lane + 1)) & 1ULL);
    return r;
}

__device__ inline int shard_of(int pix) { return (pix ^ (pix >> 6)) & (NSHARD - 1); }

// ---- K1 fused prep: img transpose + dp transpose + run count ----
constexpr int NB_IMG = (HW / 32) * (C_DIM / 32) * B_DIM;   // 1920
constexpr int NB_DP  = (HW / 32) * (D_DIM / 32) * B_DIM;   // 960
constexpr int NB_CNT = NPTS / 256;                         // 3840
__global__ __launch_bounds__(256) void k_prep(const float* __restrict__ img,
                                              const float* __restrict__ dp,
                                              const float* __restrict__ dv,
                                              const float* __restrict__ K,
                                              const float* __restrict__ T,
                                              float* __restrict__ img_t,
                                              float* __restrict__ dp_t,
                                              int* __restrict__ hist2) {
    int bid = blockIdx.x;
    if (bid < NB_IMG + NB_DP) {
        // tiled 32x32 transpose: src[b, r, pix] -> dst[b, pix, r]
        const float* src; float* dst; int rows;
        if (bid < NB_IMG) { src = img; dst = img_t; rows = C_DIM; }
        else              { bid -= NB_IMG; src = dp; dst = dp_t; rows = D_DIM; }
        const int tiles_c = rows / 32;
        const int b = bid / ((HW / 32) * tiles_c);
        const int r = bid % ((HW / 32) * tiles_c);
        const int ctile = r / (HW / 32), ptile = r % (HW / 32);
        __shared__ float tile[32][33];
        const int tx = threadIdx.x & 31, ty = threadIdx.x >> 5;   // (32, 8)
        const int pix0 = ptile * 32, c0 = ctile * 32;
        #pragma unroll
        for (int j = 0; j < 32; j += 8)
            tile[ty + j][tx] = src[((size_t)(b * rows + c0 + ty + j)) * HW + pix0 + tx];
        __syncthreads();
        #pragma unroll
        for (int j = 0; j < 32; j += 8)
            dst[((size_t)(b * HW + pix0 + ty + j)) * rows + c0 + tx] = tile[tx][ty + j];
    } else {
        // count merged runs; wave = one ray, lane = depth bin
        const int tid = (bid - NB_IMG - NB_DP) * 256 + threadIdx.x;   // < NPTS
        const int lane = threadIdx.x & 63;                            // = d
        const int wid = tid >> 6;                                     // ray id
        const int b = wid / HW, pix = wid % HW;
        const int gcell = gcell_ray(b, pix, lane, dv, K, T);
        const RunInfo ri = wave_runs_d(gcell, lane);
        if (ri.is_tail && gcell >= 0)
            atomicAdd(&hist2[(size_t)shard_of(pix) * NCELL_TOT + gcell], 1);
    }
}

// ---- K2: reduce shards -> per-cell totals ----
__global__ __launch_bounds__(256) void k_reduce(const int* __restrict__ hist2,
                                                int* __restrict__ hist) {
    const int cell = blockIdx.x * 256 + threadIdx.x;  // 128 blocks exact
    int s = 0;
    #pragma unroll
    for (int sh = 0; sh < NSHARD; ++sh)
        s += hist2[(size_t)sh * NCELL_TOT + cell];
    hist[cell] = s;
}

// ---- K3: exclusive prefix scan over hist[32768] -> offs[32769] ----
__global__ __launch_bounds__(1024) void k_scan(const int* __restrict__ hist,
                                               int* __restrict__ offs) {
    __shared__ int lds[1024];
    const int t = threadIdx.x;
    int h[32];
    int s = 0;
    const int base = t * 32;
    #pragma unroll
    for (int k = 0; k < 32; ++k) { h[k] = hist[base + k]; s += h[k]; }
    lds[t] = s;
    __syncthreads();
    for (int off = 1; off < 1024; off <<= 1) {
        int v = (t >= off) ? lds[t - off] : 0;
        __syncthreads();
        lds[t] += v;
        __syncthreads();
    }
    int run = lds[t] - s;
    #pragma unroll
    for (int k = 0; k < 32; ++k) {
        offs[base + k] = run;
        run += h[k];
    }
    if (t == 1023) offs[NCELL_TOT] = lds[1023];
}

// ---- K4: per-cell shard prefix; hist2 becomes cursor bases in place ----
__global__ __launch_bounds__(256) void k_shardbase(int* __restrict__ hist2,
                                                   const int* __restrict__ offs) {
    const int cell = blockIdx.x * 256 + threadIdx.x;  // 128 blocks exact
    int run = offs[cell];
    #pragma unroll
    for (int sh = 0; sh < NSHARD; ++sh) {
        const size_t idx = (size_t)sh * NCELL_TOT + cell;
        const int cnt = hist2[idx];
        hist2[idx] = run;
        run += cnt;
    }
}

// ---- K5: fill merged entries. Wave = one ray; segmented inclusive scan of dp
// over equal-cell runs; run tail emits (key, summed weight). ----
__global__ __launch_bounds__(256) void k_fill(const float* __restrict__ dp_t,
                                              const float* __restrict__ dv,
                                              const float* __restrict__ K,
                                              const float* __restrict__ T,
                                              int* __restrict__ cursor2,   // = hist2 (bases)
                                              int* __restrict__ ekey,
                                              unsigned short* __restrict__ ew16) {
    const int tid = blockIdx.x * 256 + threadIdx.x;   // < NPTS
    const int lane = threadIdx.x & 63;                // = d
    const int wid = tid >> 6;                         // ray id
    const int b = wid / HW, pix = wid % HW;
    const int gcell = gcell_ray(b, pix, lane, dv, K, T);
    const RunInfo ri = wave_runs_d(gcell, lane);
    const float p = dp_t[((size_t)(b * HW + pix)) * D_DIM + lane];   // lane-contiguous
    // segmented inclusive scan (Hillis-Steele with head clamp)
    float val = p;
    #pragma unroll
    for (int dlt = 1; dlt < 64; dlt <<= 1) {
        const float up = __shfl_up(val, dlt);
        val = (lane - dlt >= ri.leader_idx) ? val + up : val;
    }
    if (ri.is_tail && gcell >= 0) {
        const int slot = atomicAdd(&cursor2[(size_t)shard_of(pix) * NCELL_TOT + gcell], 1);
        ekey[slot] = (gcell << 13) | pix;
        ew16[slot] = (unsigned short)__float2uint_rn(fminf(val * 65535.0f, 65535.0f));
    }
}

// ---- K6: chunked segmented reduction. One 64-entry chunk per 64-thread block
// (round-8 proven shape); thread = 2 channels (float2); flushes to cell-major
// out_t (128 consecutive floats per flush). Blocks past total exit early. ----
__global__ __launch_bounds__(64) void k_gather(
    const float* __restrict__ img_t,
    const int* __restrict__ offs,     // offs[NCELL_TOT] = total entry count
    const int* __restrict__ ekey,
    const unsigned short* __restrict__ ew16,
    float* __restrict__ out_t)
{
    const int total = offs[NCELL_TOT];
    const int base = blockIdx.x * CHUNK;
    if (base >= total) return;

    __shared__ int   s_key[CHUNK];
    __shared__ float s_w[CHUNK];
    {
        const int i = threadIdx.x;                    // 64 threads, CHUNK=64
        const int idx = min(base + i, total - 1);
        s_key[i] = ekey[idx];                         // pad = dup of last key
        s_w[i]   = (base + i < total) ? (float)ew16[base + i] * (1.0f / 65535.0f)
                                      : 0.0f;         // pad weight 0 -> no-op
    }
    __syncthreads();

    const int c2 = threadIdx.x * 2;                   // channels c2, c2+1
    int prev = s_key[0] >> 13;
    float2 acc = make_float2(0.0f, 0.0f);
    #pragma unroll 8
    for (int k = 0; k < CHUNK; ++k) {                 // static trip count -> pipelined
        const int key = s_key[k];                     // LDS broadcast (wave-uniform)
        const float wgt = s_w[k];
        const int gcell = key >> 13;
        const int pix = key & 8191;
        const int b = gcell >> 14;
        const float2 v = *reinterpret_cast<const float2*>(
            &img_t[((size_t)(b * HW + pix)) * C_DIM + c2]);   // 8B/lane, coalesced
        if (gcell != prev) {                          // wave-uniform branch
            float* o = &out_t[(size_t)prev * C_DIM + c2];
            atomicAdd(o, acc.x);
            atomicAdd(o + 1, acc.y);
            acc = make_float2(0.0f, 0.0f);
            prev = gcell;
        }
        acc.x = fmaf(v.x, wgt, acc.x);
        acc.y = fmaf(v.y, wgt, acc.y);
    }
    float* o = &out_t[(size_t)prev * C_DIM + c2];
    atomicAdd(o, acc.x);
    atomicAdd(o + 1, acc.y);
}

// ---- K7: untranspose out_t[b][cell][c] -> out[b][c][cell] ----
__global__ __launch_bounds__(256) void k_untranspose(const float* __restrict__ out_t,
                                                     float* __restrict__ out) {
    __shared__ float tile[32][33];
    const int b = blockIdx.z;
    const int tx = threadIdx.x, ty = threadIdx.y;      // block (32, 8)
    const int cell0 = blockIdx.x * 32, c0 = blockIdx.y * 32;
    const float* src = out_t + (size_t)b * NCELL * C_DIM;
    #pragma unroll
    for (int j = 0; j < 32; j += 8)
        tile[ty + j][tx] = src[((size_t)(cell0 + ty + j)) * C_DIM + c0 + tx];
    __syncthreads();
    #pragma unroll
    for (int j = 0; j < 32; j += 8)
        out[((size_t)(b * C_DIM + c0 + ty + j)) * NCELL + cell0 + tx] = tile[tx][ty + j];
}

extern "C" void kernel_launch(void* const* d_in, const int* in_sizes, int n_in,
                              void* d_out, int out_size, void* d_ws, size_t ws_size,
                              hipStream_t stream) {
    const float* img = (const float*)d_in[0];
    const float* dp  = (const float*)d_in[1];
    const float* dv  = (const float*)d_in[2];
    const float* K   = (const float*)d_in[3];
    const float* T   = (const float*)d_in[4];
    float* out = (float*)d_out;

    float* ws_f   = (float*)d_ws;
    float* img_t  = ws_f + WS_IMG_T;
    float* dp_t   = ws_f + WS_DP_T;
    int*   hist2  = (int*)d_ws + WS_HIST2;
    float* out_t  = ws_f + WS_OUT_T;
    int*   hist   = (int*)d_ws + WS_HIST;
    int*   offs   = (int*)d_ws + WS_OFFS;
    int*   ekey   = (int*)d_ws + WS_EKEY;
    unsigned short* ew16 = (unsigned short*)((int*)d_ws + WS_EW16);

    // hist2 and out_t adjacent -> one fused memset (8 MB + 16 MB)
    hipMemsetAsync(hist2, 0,
                   ((size_t)NSHARD * NCELL_TOT + (size_t)NCELL_TOT * C_DIM) * sizeof(int),
                   stream);

    k_prep<<<NB_IMG + NB_DP + NB_CNT, 256, 0, stream>>>(img, dp, dv, K, T,
                                                        img_t, dp_t, hist2);
    k_reduce<<<NCELL_TOT / 256, 256, 0, stream>>>(hist2, hist);
    k_scan<<<1, 1024, 0, stream>>>(hist, offs);
    k_shardbase<<<NCELL_TOT / 256, 256, 0, stream>>>(hist2, offs);
    k_fill<<<NPTS / 256, 256, 0, stream>>>(dp_t, dv, K, T, hist2, ekey, ew16);
    k_gather<<<NPTS / CHUNK, 64, 0, stream>>>(img_t, offs, ekey, ew16, out_t);
    k_untranspose<<<dim3(NCELL / 32, C_DIM / 32, B_DIM), dim3(32, 8), 0, stream>>>(
        out_t, out);
}